// Round 14
// baseline (230.786 us; speedup 1.0000x reference)
//
#include <hip/hip_runtime.h>
#include <hip/hip_bf16.h>

#define F_DIM 128
#define POOL_SEG 16

typedef __attribute__((ext_vector_type(8))) short short8v;   // 8 bf16
typedef __attribute__((ext_vector_type(4))) float float4v;   // MFMA acc

// ---------------- helpers ----------------

__device__ __forceinline__ ushort f2bf(float f) {  // RNE f32 -> bf16
    uint u = __float_as_uint(f);
    u += 0x7fffu + ((u >> 16) & 1u);
    return (ushort)(u >> 16);
}
__device__ __forceinline__ float bf2f(ushort h) {
    return __uint_as_float(((uint)h) << 16);
}
__device__ __forceinline__ void bf2x(uint u, float& a, float& b) {
    a = __uint_as_float((u & 0x0000ffffu) << 16);
    b = __uint_as_float(u & 0xffff0000u);
}

// ---------------- prep: W^T hi/lo split (blocks 0..47) + zero deg (blocks 48+) ----------------

__global__ __launch_bounds__(256) void prep_kernel(
    const float* __restrict__ W0, const float* __restrict__ W1, const float* __restrict__ W2,
    ushort* __restrict__ Wth, ushort* __restrict__ Wtl, int* __restrict__ deg, int N_)
{
    if (blockIdx.x >= 48) {
        int i = (blockIdx.x - 48) * 256 + threadIdx.x;
        if (i < N_) deg[i] = 0;
        return;
    }
    int layer = blockIdx.x >> 4;
    int chunkc = blockIdx.x & 15;
    const float* W = (layer == 0) ? W0 : (layer == 1) ? W1 : W2;
    int t = threadIdx.x;
    int c  = chunkc * 8 + (t >> 5);      // column of W
    int k0 = (t & 31) * 4;               // 4 consecutive k
    ushort4 hi, lo;
    float v0 = W[(size_t)(k0 + 0) * F_DIM + c];
    float v1 = W[(size_t)(k0 + 1) * F_DIM + c];
    float v2 = W[(size_t)(k0 + 2) * F_DIM + c];
    float v3 = W[(size_t)(k0 + 3) * F_DIM + c];
    hi.x = f2bf(v0); lo.x = f2bf(v0 - bf2f(hi.x));
    hi.y = f2bf(v1); lo.y = f2bf(v1 - bf2f(hi.y));
    hi.z = f2bf(v2); lo.z = f2bf(v2 - bf2f(hi.z));
    hi.w = f2bf(v3); lo.w = f2bf(v3 - bf2f(hi.w));
    size_t o = (size_t)layer * F_DIM * F_DIM + (size_t)c * F_DIM + k0;
    *reinterpret_cast<ushort4*>(&Wth[o]) = hi;
    *reinterpret_cast<ushort4*>(&Wtl[o]) = lo;
}

// ---------------- CSR: count + single-pass scan + fill ----------------

__global__ void count_kernel(const int* __restrict__ dst, int* __restrict__ deg, int E_) {
    int i = blockIdx.x * blockDim.x + threadIdx.x;
    if (i < E_) atomicAdd(&deg[dst[i]], 1);
}

__global__ void scan_final_kernel(const int* __restrict__ deg,
                                  int* __restrict__ row_ptr, int* __restrict__ rfill,
                                  float* __restrict__ dinv, int N_, int E_) {
    __shared__ int s[256];
    __shared__ int sred[256];
    const int t = threadIdx.x;
    const int bid = blockIdx.x;
    const int i = bid * 256 + t;
    const int pre_end = bid * 256;

    // block prefix: sum of deg[0 .. bid*256)
    int pv = 0;
    for (int j = t; j < pre_end; j += 256) pv += deg[j];
    sred[t] = pv;
    __syncthreads();
    for (int off = 128; off; off >>= 1) {
        if (t < off) sred[t] += sred[t + off];
        __syncthreads();
    }
    const int bpre = sred[0];

    int orig = (i < N_) ? deg[i] : 0;
    s[t] = orig;
    __syncthreads();
    for (int off = 1; off < 256; off <<= 1) {
        int v = (t >= off) ? s[t - off] : 0;
        __syncthreads();
        s[t] += v;
        __syncthreads();
    }
    int excl = s[t] - orig + bpre;
    if (i < N_) {
        row_ptr[i] = excl;
        rfill[i] = excl;
        dinv[i] = 1.0f / sqrtf((float)(orig + 1));   // +1 self-loop
    }
    if (i == N_ - 1) row_ptr[N_] = E_;
}

__global__ void fill_kernel(const int* __restrict__ src, const int* __restrict__ dst,
                            int* __restrict__ cur, int* __restrict__ col_src, int E_) {
    int i = blockIdx.x * blockDim.x + threadIdx.x;
    if (i < E_) {
        int p = atomicAdd(&cur[dst[i]], 1);
        col_src[p] = src[i];
    }
}

// ---------------- MFMA GEMM: Mbf[r][c] = bf16( dinv[r] * sum_k in[r][k] * W[k][c] ) ----------------
// bf16 hi/lo split, 3-term (AhBh + AlBh + AhBl) -> ~f32 accuracy.

__global__ __launch_bounds__(256) void gemm_scale_kernel(
    const float* __restrict__ in, const ushort* __restrict__ Wth, const ushort* __restrict__ Wtl,
    const float* __restrict__ dinv, ushort* __restrict__ outbf, int N_)
{
    __shared__ ushort Ah[64 * F_DIM];   // 16 KB each, XOR-swizzled k within row
    __shared__ ushort Al[64 * F_DIM];
    __shared__ ushort Bh[64 * F_DIM];   // [c][k]
    __shared__ ushort Bl[64 * F_DIM];

    const int tid = threadIdx.x;
    const int brow = (blockIdx.x >> 1) * 64;
    const int bcol = (blockIdx.x & 1) * 64;

    #pragma unroll
    for (int i = 0; i < 4; ++i) {
        int chunk = tid + i * 256;
        int r  = chunk >> 4;
        int k0 = (chunk & 15) * 8;
        int row = brow + r;
        float f[8];
        if (row < N_) {
            float4 g0 = *reinterpret_cast<const float4*>(&in[(size_t)row * F_DIM + k0]);
            float4 g1 = *reinterpret_cast<const float4*>(&in[(size_t)row * F_DIM + k0 + 4]);
            f[0] = g0.x; f[1] = g0.y; f[2] = g0.z; f[3] = g0.w;
            f[4] = g1.x; f[5] = g1.y; f[6] = g1.z; f[7] = g1.w;
        } else {
            #pragma unroll
            for (int j = 0; j < 8; ++j) f[j] = 0.f;
        }
        ushort hi[8], lo[8];
        #pragma unroll
        for (int j = 0; j < 8; ++j) {
            hi[j] = f2bf(f[j]);
            lo[j] = f2bf(f[j] - bf2f(hi[j]));
        }
        int idx = r * F_DIM + (k0 ^ ((r & 7) << 3));
        *reinterpret_cast<short8v*>(&Ah[idx]) = *reinterpret_cast<short8v*>(hi);
        *reinterpret_cast<short8v*>(&Al[idx]) = *reinterpret_cast<short8v*>(lo);
    }
    #pragma unroll
    for (int i = 0; i < 4; ++i) {
        int chunk = tid + i * 256;
        int c  = chunk >> 4;
        int k0 = (chunk & 15) * 8;
        size_t go = (size_t)(bcol + c) * F_DIM + k0;
        int idx = c * F_DIM + (k0 ^ ((c & 7) << 3));
        *reinterpret_cast<short8v*>(&Bh[idx]) = *reinterpret_cast<const short8v*>(&Wth[go]);
        *reinterpret_cast<short8v*>(&Bl[idx]) = *reinterpret_cast<const short8v*>(&Wtl[go]);
    }
    __syncthreads();

    const int l = tid & 63;
    const int wave = tid >> 6;
    const int m0 = wave * 16;
    const int row_a = m0 + (l & 15);
    const int kgrp = (l >> 4) * 8;
    const int aswz = (row_a & 7) << 3;

    float4v acc[4] = {{0.f,0.f,0.f,0.f},{0.f,0.f,0.f,0.f},{0.f,0.f,0.f,0.f},{0.f,0.f,0.f,0.f}};

    #pragma unroll
    for (int kk = 0; kk < 4; ++kk) {
        int kbase = kk * 32 + kgrp;
        short8v a_h = *reinterpret_cast<short8v*>(&Ah[row_a * F_DIM + (kbase ^ aswz)]);
        short8v a_l = *reinterpret_cast<short8v*>(&Al[row_a * F_DIM + (kbase ^ aswz)]);
        #pragma unroll
        for (int n = 0; n < 4; ++n) {
            int col_b = n * 16 + (l & 15);
            int bidx = col_b * F_DIM + (kbase ^ ((col_b & 7) << 3));
            short8v b_h = *reinterpret_cast<short8v*>(&Bh[bidx]);
            short8v b_l = *reinterpret_cast<short8v*>(&Bl[bidx]);
            acc[n] = __builtin_amdgcn_mfma_f32_16x16x32_bf16(a_h, b_h, acc[n], 0, 0, 0);
            acc[n] = __builtin_amdgcn_mfma_f32_16x16x32_bf16(a_l, b_h, acc[n], 0, 0, 0);
            acc[n] = __builtin_amdgcn_mfma_f32_16x16x32_bf16(a_h, b_l, acc[n], 0, 0, 0);
        }
    }

    #pragma unroll
    for (int i = 0; i < 4; ++i) {
        int rloc = m0 + (l >> 4) * 4 + i;
        int row = brow + rloc;
        if (row < N_) {
            float s = dinv[row];
            #pragma unroll
            for (int n = 0; n < 4; ++n) {
                ushort o = f2bf(s * acc[n][i]);
                outbf[(size_t)row * F_DIM + bcol + n * 16 + (l & 15)] = o;
            }
        }
    }
}

// ---------------- Gather-aggregate + bias + relu (bf16 messages, burst uint4 loads) ----------------
// Tail issues exactly ceil(rem/4) batched loads (wave-uniform branch) instead of
// always 4 — removes ~26% duplicate clamped wave-loads vs R8. Sums bit-identical.

#define ACCUM(u, m)                                                        \
    { float a_, b_;                                                        \
      bf2x((u).x, a_, b_); acc[0] = fmaf(a_, (m), acc[0]); acc[1] = fmaf(b_, (m), acc[1]); \
      bf2x((u).y, a_, b_); acc[2] = fmaf(a_, (m), acc[2]); acc[3] = fmaf(b_, (m), acc[3]); \
      bf2x((u).z, a_, b_); acc[4] = fmaf(a_, (m), acc[4]); acc[5] = fmaf(b_, (m), acc[5]); \
      bf2x((u).w, a_, b_); acc[6] = fmaf(a_, (m), acc[6]); acc[7] = fmaf(b_, (m), acc[7]); }

#define ACCUM1(u)                                                          \
    { float a_, b_;                                                        \
      bf2x((u).x, a_, b_); acc[0] += a_; acc[1] += b_;                     \
      bf2x((u).y, a_, b_); acc[2] += a_; acc[3] += b_;                     \
      bf2x((u).z, a_, b_); acc[4] += a_; acc[5] += b_;                     \
      bf2x((u).w, a_, b_); acc[6] += a_; acc[7] += b_; }

__global__ __launch_bounds__(256) void gather_kernel(
    const ushort* __restrict__ Mbf, const int* __restrict__ row_ptr,
    const int* __restrict__ col_src, const float* __restrict__ dinv,
    const float* __restrict__ bias, float* __restrict__ Hout, int N_)
{
    int v = blockIdx.x * 4 + (threadIdx.x >> 6);
    if (v >= N_) return;
    const int lane = threadIdx.x & 63;
    const int fq  = lane & 15;      // uint4 index within row (16 x 16B = 256B)
    const int sub = lane >> 4;      // load slot 0..3
    const uint4* M4 = reinterpret_cast<const uint4*>(Mbf);   // row stride 16

    float acc[8];
    #pragma unroll
    for (int j = 0; j < 8; ++j) acc[j] = 0.f;

    int lo = row_ptr[v];
    int total = row_ptr[v + 1] - lo + 1;    // self + in-edges

    for (int base = 0; base < total; base += 64) {
        int nidx = total - base; if (nidx > 64) nidx = 64;
        int p = base + lane;
        int idx = v;                         // position 0 of chunk 0 = self loop
        if (p > 0 && p < total) idx = col_src[lo + p - 1];

        int nslots = (nidx + 3) >> 2;        // slots of 4 positions
        int jfull  = (nidx >> 4) * 4;        // slots covered by COMPLETE 16-pos groups
        int j = 0;
        for (; j < jfull; j += 4) {
            int q0 = j * 4 + sub;
            int s0 = __shfl(idx, q0);
            int s1 = __shfl(idx, q0 + 4);
            int s2 = __shfl(idx, q0 + 8);
            int s3 = __shfl(idx, q0 + 12);
            uint4 u0 = M4[(size_t)s0 * 16 + fq];
            uint4 u1 = M4[(size_t)s1 * 16 + fq];
            uint4 u2 = M4[(size_t)s2 * 16 + fq];
            uint4 u3 = M4[(size_t)s3 * 16 + fq];
            ACCUM1(u0); ACCUM1(u1); ACCUM1(u2); ACCUM1(u3);
        }
        int rems = nslots - j;               // 0..4, wave-uniform
        if (rems > 0) {
            int q0 = j * 4 + sub;
            int q1 = q0 + 4, q2 = q0 + 8, q3 = q0 + 12;
            int c0 = min(q0, nidx - 1), c1 = min(q1, nidx - 1);
            int c2 = min(q2, nidx - 1), c3 = min(q3, nidx - 1);
            int s0 = __shfl(idx, c0);
            int s1 = __shfl(idx, c1);
            int s2 = __shfl(idx, c2);
            int s3 = __shfl(idx, c3);
            float m0 = (q0 < nidx) ? 1.f : 0.f;
            float m1 = (q1 < nidx) ? 1.f : 0.f;
            float m2 = (q2 < nidx) ? 1.f : 0.f;
            float m3 = (q3 < nidx) ? 1.f : 0.f;
            if (rems == 4) {
                uint4 u0 = M4[(size_t)s0 * 16 + fq];
                uint4 u1 = M4[(size_t)s1 * 16 + fq];
                uint4 u2 = M4[(size_t)s2 * 16 + fq];
                uint4 u3 = M4[(size_t)s3 * 16 + fq];
                ACCUM(u0, m0); ACCUM(u1, m1); ACCUM(u2, m2); ACCUM(u3, m3);
            } else if (rems == 3) {
                uint4 u0 = M4[(size_t)s0 * 16 + fq];
                uint4 u1 = M4[(size_t)s1 * 16 + fq];
                uint4 u2 = M4[(size_t)s2 * 16 + fq];
                ACCUM(u0, m0); ACCUM(u1, m1); ACCUM(u2, m2);
            } else if (rems == 2) {
                uint4 u0 = M4[(size_t)s0 * 16 + fq];
                uint4 u1 = M4[(size_t)s1 * 16 + fq];
                ACCUM(u0, m0); ACCUM(u1, m1);
            } else {
                uint4 u0 = M4[(size_t)s0 * 16 + fq];
                ACCUM(u0, m0);
            }
        }
    }

    #pragma unroll
    for (int j = 0; j < 8; ++j) {
        acc[j] += __shfl_xor(acc[j], 16);
        acc[j] += __shfl_xor(acc[j], 32);
    }

    if (sub == 0) {
        float dv = dinv[v];
        const float4* b4 = reinterpret_cast<const float4*>(bias);
        float4 bb0 = b4[fq * 2], bb1 = b4[fq * 2 + 1];
        float4 o0, o1;
        o0.x = fmaxf(dv * acc[0] + bb0.x, 0.0f);
        o0.y = fmaxf(dv * acc[1] + bb0.y, 0.0f);
        o0.z = fmaxf(dv * acc[2] + bb0.z, 0.0f);
        o0.w = fmaxf(dv * acc[3] + bb0.w, 0.0f);
        o1.x = fmaxf(dv * acc[4] + bb1.x, 0.0f);
        o1.y = fmaxf(dv * acc[5] + bb1.y, 0.0f);
        o1.z = fmaxf(dv * acc[6] + bb1.z, 0.0f);
        o1.w = fmaxf(dv * acc[7] + bb1.w, 0.0f);
        float4* H4 = reinterpret_cast<float4*>(&Hout[(size_t)v * F_DIM + fq * 8]);
        H4[0] = o0;
        H4[1] = o1;
    }
}

// ---------------- Mean-pool per graph + final linear (two-stage, deterministic) ----------------

__device__ __forceinline__ int lower_bound_i(const int* __restrict__ a, int n, int key) {
    int lo = 0, hi = n;
    while (lo < hi) {
        int mid = (lo + hi) >> 1;
        if (a[mid] < key) lo = mid + 1; else hi = mid;
    }
    return lo;
}

__global__ __launch_bounds__(128) void pool_part_kernel(
    const float* __restrict__ H, const int* __restrict__ batch,
    float* __restrict__ partial, int N_)
{
    int g = blockIdx.x / POOL_SEG;
    int s = blockIdx.x % POOL_SEG;
    int lo = lower_bound_i(batch, N_, g);
    int hi = lower_bound_i(batch, N_, g + 1);
    int len = hi - lo;
    int chunk = (len + POOL_SEG - 1) / POOL_SEG;
    int a = lo + s * chunk;
    int b = min(a + chunk, hi);
    int col = threadIdx.x;
    float acc = 0.f;
    for (int n = a; n < b; ++n) acc += H[(size_t)n * F_DIM + col];
    partial[((size_t)g * POOL_SEG + s) * F_DIM + col] = acc;
}

__global__ __launch_bounds__(128) void pool_final_kernel(
    const float* __restrict__ partial, const int* __restrict__ batch,
    const float* __restrict__ lin_w, const float* __restrict__ lin_b,
    float* __restrict__ out, int N_)
{
    int g = blockIdx.x;
    int col = threadIdx.x;
    float acc = 0.f;
    #pragma unroll
    for (int s = 0; s < POOL_SEG; ++s)
        acc += partial[((size_t)g * POOL_SEG + s) * F_DIM + col];
    int lo = lower_bound_i(batch, N_, g);
    int hi = lower_bound_i(batch, N_, g + 1);
    float pooled = acc / fmaxf((float)(hi - lo), 1.0f);
    float v = pooled * lin_w[col];
    __shared__ float sm[128];
    sm[col] = v;
    __syncthreads();
    if (col < 64) {
        float t = sm[col] + sm[col + 64];
        for (int off = 32; off; off >>= 1) t += __shfl_down(t, off);
        if (col == 0) out[g] = t + lin_b[0];
    }
}

// ---------------- Launch ----------------

extern "C" void kernel_launch(void* const* d_in, const int* in_sizes, int n_in,
                              void* d_out, int out_size, void* d_ws, size_t ws_size,
                              hipStream_t stream) {
    const float* x     = (const float*)d_in[0];
    const int*   ei    = (const int*)d_in[1];
    const int*   batch = (const int*)d_in[2];
    const float* W0    = (const float*)d_in[3];
    const float* b0    = (const float*)d_in[4];
    const float* W1    = (const float*)d_in[5];
    const float* b1    = (const float*)d_in[6];
    const float* W2    = (const float*)d_in[7];
    const float* b2    = (const float*)d_in[8];
    const float* lin_w = (const float*)d_in[9];
    const float* lin_b = (const float*)d_in[10];

    const int N_ = in_sizes[2];
    const int E_ = in_sizes[1] / 2;
    const int G_ = out_size;
    const int* esrc = ei;
    const int* edst = ei + E_;

    // workspace layout (bytes from d_ws)
    char* p = reinterpret_cast<char*>(d_ws);
    ushort* Mbf = reinterpret_cast<ushort*>(p);        p += (size_t)N_ * F_DIM * sizeof(ushort);
    float*  Hbuf = reinterpret_cast<float*>(p);        p += (size_t)N_ * F_DIM * sizeof(float);
    float*  dinvp = reinterpret_cast<float*>(p);       p += (size_t)N_ * sizeof(float);
    int*    deg = reinterpret_cast<int*>(p);           p += (size_t)N_ * sizeof(int);
    int*    row_ptr = reinterpret_cast<int*>(p);       p += (size_t)(N_ + 4) * sizeof(int);
    int*    rfill = reinterpret_cast<int*>(p);         p += (size_t)N_ * sizeof(int);
    int*    col_src = reinterpret_cast<int*>(p);       p += (size_t)E_ * sizeof(int);
    ushort* Wth = reinterpret_cast<ushort*>(p);        p += (size_t)3 * F_DIM * F_DIM * sizeof(ushort);
    ushort* Wtl = reinterpret_cast<ushort*>(p);        p += (size_t)3 * F_DIM * F_DIM * sizeof(ushort);
    float*  partial = reinterpret_cast<float*>(d_ws);  // alias Mbf region (dead during pooling)

    const int NB = (N_ + 255) / 256;
    const int eb = (E_ + 255) / 256;
    const int gemm_grid = ((N_ + 63) / 64) * 2;
    const int gat_grid  = (N_ + 3) / 4;

    prep_kernel<<<48 + NB, 256, 0, stream>>>(W0, W1, W2, Wth, Wtl, deg, N_);
    count_kernel<<<eb, 256, 0, stream>>>(edst, deg, E_);
    scan_final_kernel<<<NB, 256, 0, stream>>>(deg, row_ptr, rfill, dinvp, N_, E_);
    fill_kernel<<<eb, 256, 0, stream>>>(esrc, edst, rfill, col_src, E_);

    const float* cur_in = x;
    const float* bias[3] = {b0, b1, b2};
    for (int l = 0; l < 3; ++l) {
        gemm_scale_kernel<<<gemm_grid, 256, 0, stream>>>(
            cur_in, Wth + (size_t)l * F_DIM * F_DIM, Wtl + (size_t)l * F_DIM * F_DIM,
            dinvp, Mbf, N_);
        gather_kernel<<<gat_grid, 256, 0, stream>>>(
            Mbf, row_ptr, col_src, dinvp, bias[l], Hbuf, N_);
        cur_in = Hbuf;
    }

    pool_part_kernel<<<G_ * POOL_SEG, 128, 0, stream>>>(Hbuf, batch, partial, N_);
    pool_final_kernel<<<G_, 128, 0, stream>>>(partial, batch, lin_w, lin_b, (float*)d_out, N_);
}

// Round 15
// 214.310 us; speedup vs baseline: 1.0769x; 1.0769x over previous
//
#include <hip/hip_runtime.h>
#include <hip/hip_bf16.h>

#define F_DIM 128
#define POOL_SEG 16

typedef __attribute__((ext_vector_type(8))) short short8v;   // 8 bf16
typedef __attribute__((ext_vector_type(4))) float float4v;   // MFMA acc

// ---------------- helpers ----------------

__device__ __forceinline__ ushort f2bf(float f) {  // RNE f32 -> bf16
    uint u = __float_as_uint(f);
    u += 0x7fffu + ((u >> 16) & 1u);
    return (ushort)(u >> 16);
}
__device__ __forceinline__ float bf2f(ushort h) {
    return __uint_as_float(((uint)h) << 16);
}
__device__ __forceinline__ void bf2x(uint u, float& a, float& b) {
    a = __uint_as_float((u & 0x0000ffffu) << 16);
    b = __uint_as_float(u & 0xffff0000u);
}

// ---------------- CSR build ----------------

__global__ void count_kernel(const int* __restrict__ dst, int* __restrict__ deg, int E_) {
    int i = blockIdx.x * blockDim.x + threadIdx.x;
    if (i < E_) atomicAdd(&deg[dst[i]], 1);
}

__global__ void scan_blocksums_kernel(const int* __restrict__ deg, int* __restrict__ bsum, int N_) {
    __shared__ int s[256];
    int i = blockIdx.x * 256 + threadIdx.x;
    s[threadIdx.x] = (i < N_) ? deg[i] : 0;
    __syncthreads();
    for (int off = 128; off; off >>= 1) {
        if (threadIdx.x < off) s[threadIdx.x] += s[threadIdx.x + off];
        __syncthreads();
    }
    if (threadIdx.x == 0) bsum[blockIdx.x] = s[0];
}

__global__ void scan_bs_kernel(const int* __restrict__ bsum, int* __restrict__ bsx, int NB) {
    __shared__ int s[256];
    int t = threadIdx.x;
    int orig = (t < NB) ? bsum[t] : 0;
    s[t] = orig;
    __syncthreads();
    for (int off = 1; off < 256; off <<= 1) {
        int v = (t >= off) ? s[t - off] : 0;
        __syncthreads();
        s[t] += v;
        __syncthreads();
    }
    if (t < NB) bsx[t] = s[t] - orig;   // exclusive
}

__global__ void scan_final_kernel(const int* __restrict__ deg, const int* __restrict__ bsx,
                                  int* __restrict__ row_ptr, int* __restrict__ rfill,
                                  float* __restrict__ dinv, int N_, int E_) {
    __shared__ int s[256];
    int t = threadIdx.x;
    int i = blockIdx.x * 256 + t;
    int orig = (i < N_) ? deg[i] : 0;
    s[t] = orig;
    __syncthreads();
    for (int off = 1; off < 256; off <<= 1) {
        int v = (t >= off) ? s[t - off] : 0;
        __syncthreads();
        s[t] += v;
        __syncthreads();
    }
    int excl = s[t] - orig + bsx[blockIdx.x];
    if (i < N_) {
        row_ptr[i] = excl;
        rfill[i] = excl;
        dinv[i] = 1.0f / sqrtf((float)(orig + 1));   // +1 self-loop
    }
    if (i == N_ - 1) row_ptr[N_] = E_;
}

__global__ void fill_kernel(const int* __restrict__ src, const int* __restrict__ dst,
                            int* __restrict__ cur, int* __restrict__ col_src, int E_) {
    int i = blockIdx.x * blockDim.x + threadIdx.x;
    if (i < E_) {
        int p = atomicAdd(&cur[dst[i]], 1);
        col_src[p] = src[i];
    }
}

// ---------------- prep: W^T hi/lo split (blocks 0..47) + zero deg (blocks 48+) ----------------

__global__ __launch_bounds__(256) void prep_kernel(
    const float* __restrict__ W0, const float* __restrict__ W1, const float* __restrict__ W2,
    ushort* __restrict__ Wth, ushort* __restrict__ Wtl, int* __restrict__ deg, int N_)
{
    if (blockIdx.x >= 48) {
        int i = (blockIdx.x - 48) * 256 + threadIdx.x;
        if (i < N_) deg[i] = 0;
        return;
    }
    int layer = blockIdx.x >> 4;
    int chunkc = blockIdx.x & 15;
    const float* W = (layer == 0) ? W0 : (layer == 1) ? W1 : W2;
    int t = threadIdx.x;
    int c  = chunkc * 8 + (t >> 5);      // column of W
    int k0 = (t & 31) * 4;               // 4 consecutive k
    ushort4 hi, lo;
    float v0 = W[(size_t)(k0 + 0) * F_DIM + c];
    float v1 = W[(size_t)(k0 + 1) * F_DIM + c];
    float v2 = W[(size_t)(k0 + 2) * F_DIM + c];
    float v3 = W[(size_t)(k0 + 3) * F_DIM + c];
    hi.x = f2bf(v0); lo.x = f2bf(v0 - bf2f(hi.x));
    hi.y = f2bf(v1); lo.y = f2bf(v1 - bf2f(hi.y));
    hi.z = f2bf(v2); lo.z = f2bf(v2 - bf2f(hi.z));
    hi.w = f2bf(v3); lo.w = f2bf(v3 - bf2f(hi.w));
    size_t o = (size_t)layer * F_DIM * F_DIM + (size_t)c * F_DIM + k0;
    *reinterpret_cast<ushort4*>(&Wth[o]) = hi;
    *reinterpret_cast<ushort4*>(&Wtl[o]) = lo;
}

// ---------------- MFMA GEMM: Mbf[r][c] = bf16( dinv[r] * sum_k in[r][k] * W[k][c] ) ----------------
// bf16 hi/lo split, 3-term (AhBh + AlBh + AhBl) -> ~f32 accuracy.

__global__ __launch_bounds__(256) void gemm_scale_kernel(
    const float* __restrict__ in, const ushort* __restrict__ Wth, const ushort* __restrict__ Wtl,
    const float* __restrict__ dinv, ushort* __restrict__ outbf, int N_)
{
    __shared__ ushort Ah[64 * F_DIM];   // 16 KB each, XOR-swizzled k within row
    __shared__ ushort Al[64 * F_DIM];
    __shared__ ushort Bh[64 * F_DIM];   // [c][k]
    __shared__ ushort Bl[64 * F_DIM];

    const int tid = threadIdx.x;
    const int brow = (blockIdx.x >> 1) * 64;
    const int bcol = (blockIdx.x & 1) * 64;

    #pragma unroll
    for (int i = 0; i < 4; ++i) {
        int chunk = tid + i * 256;
        int r  = chunk >> 4;
        int k0 = (chunk & 15) * 8;
        int row = brow + r;
        float f[8];
        if (row < N_) {
            float4 g0 = *reinterpret_cast<const float4*>(&in[(size_t)row * F_DIM + k0]);
            float4 g1 = *reinterpret_cast<const float4*>(&in[(size_t)row * F_DIM + k0 + 4]);
            f[0] = g0.x; f[1] = g0.y; f[2] = g0.z; f[3] = g0.w;
            f[4] = g1.x; f[5] = g1.y; f[6] = g1.z; f[7] = g1.w;
        } else {
            #pragma unroll
            for (int j = 0; j < 8; ++j) f[j] = 0.f;
        }
        ushort hi[8], lo[8];
        #pragma unroll
        for (int j = 0; j < 8; ++j) {
            hi[j] = f2bf(f[j]);
            lo[j] = f2bf(f[j] - bf2f(hi[j]));
        }
        int idx = r * F_DIM + (k0 ^ ((r & 7) << 3));
        *reinterpret_cast<short8v*>(&Ah[idx]) = *reinterpret_cast<short8v*>(hi);
        *reinterpret_cast<short8v*>(&Al[idx]) = *reinterpret_cast<short8v*>(lo);
    }
    #pragma unroll
    for (int i = 0; i < 4; ++i) {
        int chunk = tid + i * 256;
        int c  = chunk >> 4;
        int k0 = (chunk & 15) * 8;
        size_t go = (size_t)(bcol + c) * F_DIM + k0;
        int idx = c * F_DIM + (k0 ^ ((c & 7) << 3));
        *reinterpret_cast<short8v*>(&Bh[idx]) = *reinterpret_cast<const short8v*>(&Wth[go]);
        *reinterpret_cast<short8v*>(&Bl[idx]) = *reinterpret_cast<const short8v*>(&Wtl[go]);
    }
    __syncthreads();

    const int l = tid & 63;
    const int wave = tid >> 6;
    const int m0 = wave * 16;
    const int row_a = m0 + (l & 15);
    const int kgrp = (l >> 4) * 8;
    const int aswz = (row_a & 7) << 3;

    float4v acc[4] = {{0.f,0.f,0.f,0.f},{0.f,0.f,0.f,0.f},{0.f,0.f,0.f,0.f},{0.f,0.f,0.f,0.f}};

    #pragma unroll
    for (int kk = 0; kk < 4; ++kk) {
        int kbase = kk * 32 + kgrp;
        short8v a_h = *reinterpret_cast<short8v*>(&Ah[row_a * F_DIM + (kbase ^ aswz)]);
        short8v a_l = *reinterpret_cast<short8v*>(&Al[row_a * F_DIM + (kbase ^ aswz)]);
        #pragma unroll
        for (int n = 0; n < 4; ++n) {
            int col_b = n * 16 + (l & 15);
            int bidx = col_b * F_DIM + (kbase ^ ((col_b & 7) << 3));
            short8v b_h = *reinterpret_cast<short8v*>(&Bh[bidx]);
            short8v b_l = *reinterpret_cast<short8v*>(&Bl[bidx]);
            acc[n] = __builtin_amdgcn_mfma_f32_16x16x32_bf16(a_h, b_h, acc[n], 0, 0, 0);
            acc[n] = __builtin_amdgcn_mfma_f32_16x16x32_bf16(a_l, b_h, acc[n], 0, 0, 0);
            acc[n] = __builtin_amdgcn_mfma_f32_16x16x32_bf16(a_h, b_l, acc[n], 0, 0, 0);
        }
    }

    #pragma unroll
    for (int i = 0; i < 4; ++i) {
        int rloc = m0 + (l >> 4) * 4 + i;
        int row = brow + rloc;
        if (row < N_) {
            float s = dinv[row];
            #pragma unroll
            for (int n = 0; n < 4; ++n) {
                ushort o = f2bf(s * acc[n][i]);
                outbf[(size_t)row * F_DIM + bcol + n * 16 + (l & 15)] = o;
            }
        }
    }
}

// ---------------- Gather-aggregate + bias + relu (bf16, burst uint4 loads) ----------------

__global__ __launch_bounds__(256) void gather_kernel(
    const ushort* __restrict__ Mbf, const int* __restrict__ row_ptr,
    const int* __restrict__ col_src, const float* __restrict__ dinv,
    const float* __restrict__ bias, float* __restrict__ Hout, int N_)
{
    int v = blockIdx.x * 4 + (threadIdx.x >> 6);
    if (v >= N_) return;
    const int lane = threadIdx.x & 63;
    const int fq  = lane & 15;      // uint4 index within row (16 x 16B = 256B)
    const int sub = lane >> 4;      // load slot 0..3
    const uint4* M4 = reinterpret_cast<const uint4*>(Mbf);   // row stride 16

    float acc[8];
    #pragma unroll
    for (int j = 0; j < 8; ++j) acc[j] = 0.f;

    int lo = row_ptr[v];
    int total = row_ptr[v + 1] - lo + 1;    // self + in-edges

    for (int base = 0; base < total; base += 64) {
        int nidx = total - base; if (nidx > 64) nidx = 64;
        int p = base + lane;
        int idx = v;                         // position 0 of chunk 0 = self loop
        if (p > 0 && p < total) idx = col_src[lo + p - 1];

        int nslots = (nidx + 3) >> 2;        // slots of 4 positions
        int jfull  = (nidx >> 4) * 4;        // slots covered by COMPLETE 16-pos groups
        int j = 0;
        for (; j < jfull; j += 4) {
            int q0 = j * 4 + sub;
            int s0 = __shfl(idx, q0);
            int s1 = __shfl(idx, q0 + 4);
            int s2 = __shfl(idx, q0 + 8);
            int s3 = __shfl(idx, q0 + 12);
            uint4 u0 = M4[(size_t)s0 * 16 + fq];
            uint4 u1 = M4[(size_t)s1 * 16 + fq];
            uint4 u2 = M4[(size_t)s2 * 16 + fq];
            uint4 u3 = M4[(size_t)s3 * 16 + fq];
            float a, b;
            bf2x(u0.x, a, b); acc[0] += a; acc[1] += b;
            bf2x(u0.y, a, b); acc[2] += a; acc[3] += b;
            bf2x(u0.z, a, b); acc[4] += a; acc[5] += b;
            bf2x(u0.w, a, b); acc[6] += a; acc[7] += b;
            bf2x(u1.x, a, b); acc[0] += a; acc[1] += b;
            bf2x(u1.y, a, b); acc[2] += a; acc[3] += b;
            bf2x(u1.z, a, b); acc[4] += a; acc[5] += b;
            bf2x(u1.w, a, b); acc[6] += a; acc[7] += b;
            bf2x(u2.x, a, b); acc[0] += a; acc[1] += b;
            bf2x(u2.y, a, b); acc[2] += a; acc[3] += b;
            bf2x(u2.z, a, b); acc[4] += a; acc[5] += b;
            bf2x(u2.w, a, b); acc[6] += a; acc[7] += b;
            bf2x(u3.x, a, b); acc[0] += a; acc[1] += b;
            bf2x(u3.y, a, b); acc[2] += a; acc[3] += b;
            bf2x(u3.z, a, b); acc[4] += a; acc[5] += b;
            bf2x(u3.w, a, b); acc[6] += a; acc[7] += b;
        }
        if (j < nslots) {                    // tail: 1..4 valid slots
            int q0 = j * 4 + sub;
            int q1 = q0 + 4, q2 = q0 + 8, q3 = q0 + 12;
            int c0 = min(q0, nidx - 1), c1 = min(q1, nidx - 1);
            int c2 = min(q2, nidx - 1), c3 = min(q3, nidx - 1);
            int s0 = __shfl(idx, c0);
            int s1 = __shfl(idx, c1);
            int s2 = __shfl(idx, c2);
            int s3 = __shfl(idx, c3);
            float m0 = (q0 < nidx) ? 1.f : 0.f;
            float m1 = (q1 < nidx) ? 1.f : 0.f;
            float m2 = (q2 < nidx) ? 1.f : 0.f;
            float m3 = (q3 < nidx) ? 1.f : 0.f;
            uint4 u0 = M4[(size_t)s0 * 16 + fq];
            uint4 u1 = M4[(size_t)s1 * 16 + fq];
            uint4 u2 = M4[(size_t)s2 * 16 + fq];
            uint4 u3 = M4[(size_t)s3 * 16 + fq];
            float a, b;
            bf2x(u0.x, a, b); acc[0] = fmaf(a, m0, acc[0]); acc[1] = fmaf(b, m0, acc[1]);
            bf2x(u0.y, a, b); acc[2] = fmaf(a, m0, acc[2]); acc[3] = fmaf(b, m0, acc[3]);
            bf2x(u0.z, a, b); acc[4] = fmaf(a, m0, acc[4]); acc[5] = fmaf(b, m0, acc[5]);
            bf2x(u0.w, a, b); acc[6] = fmaf(a, m0, acc[6]); acc[7] = fmaf(b, m0, acc[7]);
            bf2x(u1.x, a, b); acc[0] = fmaf(a, m1, acc[0]); acc[1] = fmaf(b, m1, acc[1]);
            bf2x(u1.y, a, b); acc[2] = fmaf(a, m1, acc[2]); acc[3] = fmaf(b, m1, acc[3]);
            bf2x(u1.z, a, b); acc[4] = fmaf(a, m1, acc[4]); acc[5] = fmaf(b, m1, acc[5]);
            bf2x(u1.w, a, b); acc[6] = fmaf(a, m1, acc[6]); acc[7] = fmaf(b, m1, acc[7]);
            bf2x(u2.x, a, b); acc[0] = fmaf(a, m2, acc[0]); acc[1] = fmaf(b, m2, acc[1]);
            bf2x(u2.y, a, b); acc[2] = fmaf(a, m2, acc[2]); acc[3] = fmaf(b, m2, acc[3]);
            bf2x(u2.z, a, b); acc[4] = fmaf(a, m2, acc[4]); acc[5] = fmaf(b, m2, acc[5]);
            bf2x(u2.w, a, b); acc[6] = fmaf(a, m2, acc[6]); acc[7] = fmaf(b, m2, acc[7]);
            bf2x(u3.x, a, b); acc[0] = fmaf(a, m3, acc[0]); acc[1] = fmaf(b, m3, acc[1]);
            bf2x(u3.y, a, b); acc[2] = fmaf(a, m3, acc[2]); acc[3] = fmaf(b, m3, acc[3]);
            bf2x(u3.z, a, b); acc[4] = fmaf(a, m3, acc[4]); acc[5] = fmaf(b, m3, acc[5]);
            bf2x(u3.w, a, b); acc[6] = fmaf(a, m3, acc[6]); acc[7] = fmaf(b, m3, acc[7]);
        }
    }

    #pragma unroll
    for (int j = 0; j < 8; ++j) {
        acc[j] += __shfl_xor(acc[j], 16);
        acc[j] += __shfl_xor(acc[j], 32);
    }

    if (sub == 0) {
        float dv = dinv[v];
        const float4* b4 = reinterpret_cast<const float4*>(bias);
        float4 bb0 = b4[fq * 2], bb1 = b4[fq * 2 + 1];
        float4 o0, o1;
        o0.x = fmaxf(dv * acc[0] + bb0.x, 0.0f);
        o0.y = fmaxf(dv * acc[1] + bb0.y, 0.0f);
        o0.z = fmaxf(dv * acc[2] + bb0.z, 0.0f);
        o0.w = fmaxf(dv * acc[3] + bb0.w, 0.0f);
        o1.x = fmaxf(dv * acc[4] + bb1.x, 0.0f);
        o1.y = fmaxf(dv * acc[5] + bb1.y, 0.0f);
        o1.z = fmaxf(dv * acc[6] + bb1.z, 0.0f);
        o1.w = fmaxf(dv * acc[7] + bb1.w, 0.0f);
        float4* H4 = reinterpret_cast<float4*>(&Hout[(size_t)v * F_DIM + fq * 8]);
        H4[0] = o0;
        H4[1] = o1;
    }
}

// ---------------- Mean-pool per graph + final linear (two-stage, deterministic) ----------------

__device__ __forceinline__ int lower_bound_i(const int* __restrict__ a, int n, int key) {
    int lo = 0, hi = n;
    while (lo < hi) {
        int mid = (lo + hi) >> 1;
        if (a[mid] < key) lo = mid + 1; else hi = mid;
    }
    return lo;
}

__global__ __launch_bounds__(128) void pool_part_kernel(
    const float* __restrict__ H, const int* __restrict__ batch,
    float* __restrict__ partial, int N_)
{
    int g = blockIdx.x / POOL_SEG;
    int s = blockIdx.x % POOL_SEG;
    int lo = lower_bound_i(batch, N_, g);
    int hi = lower_bound_i(batch, N_, g + 1);
    int len = hi - lo;
    int chunk = (len + POOL_SEG - 1) / POOL_SEG;
    int a = lo + s * chunk;
    int b = min(a + chunk, hi);
    int col = threadIdx.x;
    float acc = 0.f;
    for (int n = a; n < b; ++n) acc += H[(size_t)n * F_DIM + col];
    partial[((size_t)g * POOL_SEG + s) * F_DIM + col] = acc;
}

__global__ __launch_bounds__(128) void pool_final_kernel(
    const float* __restrict__ partial, const int* __restrict__ batch,
    const float* __restrict__ lin_w, const float* __restrict__ lin_b,
    float* __restrict__ out, int N_)
{
    int g = blockIdx.x;
    int col = threadIdx.x;
    float acc = 0.f;
    #pragma unroll
    for (int s = 0; s < POOL_SEG; ++s)
        acc += partial[((size_t)g * POOL_SEG + s) * F_DIM + col];
    int lo = lower_bound_i(batch, N_, g);
    int hi = lower_bound_i(batch, N_, g + 1);
    float pooled = acc / fmaxf((float)(hi - lo), 1.0f);
    float v = pooled * lin_w[col];
    __shared__ float sm[128];
    sm[col] = v;
    __syncthreads();
    if (col < 64) {
        float t = sm[col] + sm[col + 64];
        for (int off = 32; off; off >>= 1) t += __shfl_down(t, off);
        if (col == 0) out[g] = t + lin_b[0];
    }
}

// ---------------- Launch ----------------

extern "C" void kernel_launch(void* const* d_in, const int* in_sizes, int n_in,
                              void* d_out, int out_size, void* d_ws, size_t ws_size,
                              hipStream_t stream) {
    const float* x     = (const float*)d_in[0];
    const int*   ei    = (const int*)d_in[1];
    const int*   batch = (const int*)d_in[2];
    const float* W0    = (const float*)d_in[3];
    const float* b0    = (const float*)d_in[4];
    const float* W1    = (const float*)d_in[5];
    const float* b1    = (const float*)d_in[6];
    const float* W2    = (const float*)d_in[7];
    const float* b2    = (const float*)d_in[8];
    const float* lin_w = (const float*)d_in[9];
    const float* lin_b = (const float*)d_in[10];

    const int N_ = in_sizes[2];
    const int E_ = in_sizes[1] / 2;
    const int G_ = out_size;
    const int* esrc = ei;
    const int* edst = ei + E_;

    // workspace layout (bytes from d_ws)
    char* p = reinterpret_cast<char*>(d_ws);
    ushort* Mbf = reinterpret_cast<ushort*>(p);        p += (size_t)N_ * F_DIM * sizeof(ushort);
    float*  Hbuf = reinterpret_cast<float*>(p);        p += (size_t)N_ * F_DIM * sizeof(float);
    float*  dinvp = reinterpret_cast<float*>(p);       p += (size_t)N_ * sizeof(float);
    int*    deg = reinterpret_cast<int*>(p);           p += (size_t)N_ * sizeof(int);
    int*    row_ptr = reinterpret_cast<int*>(p);       p += (size_t)(N_ + 4) * sizeof(int);
    int*    rfill = reinterpret_cast<int*>(p);         p += (size_t)N_ * sizeof(int);
    int*    col_src = reinterpret_cast<int*>(p);       p += (size_t)E_ * sizeof(int);
    ushort* Wth = reinterpret_cast<ushort*>(p);        p += (size_t)3 * F_DIM * F_DIM * sizeof(ushort);
    ushort* Wtl = reinterpret_cast<ushort*>(p);        p += (size_t)3 * F_DIM * F_DIM * sizeof(ushort);
    const int NB = (N_ + 255) / 256;
    int*    bsum = reinterpret_cast<int*>(p);          p += (size_t)NB * sizeof(int);
    int*    bsx = reinterpret_cast<int*>(p);
    float*  partial = reinterpret_cast<float*>(d_ws);  // alias Mbf region (dead during pooling)

    int eb = (E_ + 255) / 256;
    prep_kernel<<<48 + NB, 256, 0, stream>>>(W0, W1, W2, Wth, Wtl, deg, N_);
    count_kernel<<<eb, 256, 0, stream>>>(edst, deg, E_);
    scan_blocksums_kernel<<<NB, 256, 0, stream>>>(deg, bsum, N_);
    scan_bs_kernel<<<1, 256, 0, stream>>>(bsum, bsx, NB);
    scan_final_kernel<<<NB, 256, 0, stream>>>(deg, bsx, row_ptr, rfill, dinvp, N_, E_);
    fill_kernel<<<eb, 256, 0, stream>>>(esrc, edst, rfill, col_src, E_);

    const int gemm_grid = ((N_ + 63) / 64) * 2;
    const int gat_grid  = (N_ + 3) / 4;

    const float* cur_in = x;
    const float* bias[3] = {b0, b1, b2};
    for (int l = 0; l < 3; ++l) {
        gemm_scale_kernel<<<gemm_grid, 256, 0, stream>>>(
            cur_in, Wth + (size_t)l * F_DIM * F_DIM, Wtl + (size_t)l * F_DIM * F_DIM,
            dinvp, Mbf, N_);
        gather_kernel<<<gat_grid, 256, 0, stream>>>(
            Mbf, row_ptr, col_src, dinvp, bias[l], Hbuf, N_);
        cur_in = Hbuf;
    }

    pool_part_kernel<<<G_ * POOL_SEG, 128, 0, stream>>>(Hbuf, batch, partial, N_);
    pool_final_kernel<<<G_, 128, 0, stream>>>(partial, batch, lin_w, lin_b, (float*)d_out, N_);
}